// Round 1
// 321.042 us; speedup vs baseline: 1.0227x; 1.0227x over previous
//
#include <hip/hip_runtime.h>
#include <math.h>

#define N_EL 4096
#define N_NB 32
#define F_IN 5
#define EDGE_FEAT 32
#define FEAT 256
#define CUTOFF 3.0f
#define PART 4   // particles per block; grid = N_EL/PART = 1024 -> 4 blocks/CU, all resident

typedef float v4f __attribute__((ext_vector_type(4)));

// Persistent-ish blocks: each block owns PART=4 consecutive particles.
//   Phase A: geometric feats for all PART*32 neighbors (128 threads).
//   Phase B: FK2 = filter_kernel[n] @ W_gamma for all PART particles;
//            each W_gamma column load is reused across the 4 particles.
//   ONE __syncthreads for the whole block lifetime.
//   Phase C: per particle, stream Gamma+edge with nontemporal dwordx4 stores
//            (268 MB write stream, zero reuse -> no-allocate in L2).
// Thread t = (kg, dv): dv = t&63 owns cols [4dv,4dv+4), kg = t>>6 owns 8 neighbors.
__global__ __launch_bounds__(256, 4) void EdgeFeatures_kernel(
    const float* __restrict__ r,            // [N,3]
    const float* __restrict__ r_nb,         // [N,K,3]
    const float* __restrict__ filter_kernel,// [N,5,32]
    const float* __restrict__ filter_bias,  // [N,32]
    const float* __restrict__ W_gamma,      // [32,256]
    const float* __restrict__ edge_kernel_w,// [N,5,256]
    const float* __restrict__ edge_bias,    // [N,256]
    const int*   __restrict__ s,            // [N]
    const int*   __restrict__ s_nb,         // [N,K]
    float*       __restrict__ out)          // Gamma [N,K,256] ++ edge [N,K,256]
{
    const int n0 = blockIdx.x * PART;
    const int t = threadIdx.x;

    // feats padded to 8 floats/neighbor: dx,dy,dz,dist,same,env,0,0
    __shared__ __align__(16) float feats[PART][N_NB * 8];   //  4 KB
    // FK2 columns + bias: rows 0..4 = g_f, row 5 = bias
    __shared__ __align__(16) float fk2[PART][6 * FEAT];     // 24 KB

    // ---- Phase A: per-neighbor geometric features (threads 0..127)
    if (t < PART * N_NB) {
        const int p = t >> 5;
        const int k = t & 31;
        const int n = n0 + p;
        const float rx = r[n * 3 + 0], ry = r[n * 3 + 1], rz = r[n * 3 + 2];
        const float* rb = r_nb + ((size_t)n * N_NB + k) * 3;
        const float dx = rb[0] - rx, dy = rb[1] - ry, dz = rb[2] - rz;
        const float dist = sqrtf(dx * dx + dy * dy + dz * dz);
        const float same = (s[n] == s_nb[n * N_NB + k]) ? 1.0f : 0.0f;
        const float x = fminf(dist * (1.0f / CUTOFF), 1.0f);
        const float env = (dist < CUTOFF)
                              ? 0.5f * (cosf(3.14159265358979323846f * x) + 1.0f)
                              : 0.0f;
        float4 a; a.x = dx; a.y = dy; a.z = dz; a.w = dist;
        float4 b; b.x = same; b.y = env; b.z = 0.0f; b.w = 0.0f;
        *reinterpret_cast<float4*>(&feats[p][k * 8 + 0]) = a;
        *reinterpret_cast<float4*>(&feats[p][k * 8 + 4]) = b;
    }

    // ---- Phase B: FK2 column t for all PART particles.
    // Each W_gamma[e*FEAT+t] load (coalesced, L2-resident) feeds 4 particles.
    {
        const float* fk = filter_kernel + (size_t)n0 * (F_IN * EDGE_FEAT); // wave-uniform
        const float* fb = filter_bias + (size_t)n0 * EDGE_FEAT;            // wave-uniform
        float acc[PART][6];
#pragma unroll
        for (int p = 0; p < PART; ++p)
#pragma unroll
            for (int q = 0; q < 6; ++q) acc[p][q] = 0.0f;

#pragma unroll 4
        for (int e = 0; e < EDGE_FEAT; ++e) {
            const float w = W_gamma[e * FEAT + t];
#pragma unroll
            for (int p = 0; p < PART; ++p) {
                const float* fkp = fk + p * (F_IN * EDGE_FEAT);
                const float* fbp = fb + p * EDGE_FEAT;
                acc[p][0] += fkp[0 * EDGE_FEAT + e] * w;
                acc[p][1] += fkp[1 * EDGE_FEAT + e] * w;
                acc[p][2] += fkp[2 * EDGE_FEAT + e] * w;
                acc[p][3] += fkp[3 * EDGE_FEAT + e] * w;
                acc[p][4] += fkp[4 * EDGE_FEAT + e] * w;
                acc[p][5] += fbp[e] * w;
            }
        }
#pragma unroll
        for (int p = 0; p < PART; ++p) {
            fk2[p][0 * FEAT + t] = acc[p][0];
            fk2[p][1 * FEAT + t] = acc[p][1];
            fk2[p][2 * FEAT + t] = acc[p][2];
            fk2[p][3 * FEAT + t] = acc[p][3];
            fk2[p][4 * FEAT + t] = acc[p][4];
            fk2[p][5 * FEAT + t] = acc[p][5];
        }
    }

    __syncthreads();  // the ONLY barrier for the whole block

    const int dv = t & 63;
    const int kg = t >> 6;
    const int d0 = dv * 4;

    // ---- Phase C: stream outputs for the 4 particles
#pragma unroll
    for (int p = 0; p < PART; ++p) {
        const int n = n0 + p;
        const float* ek = edge_kernel_w + (size_t)n * F_IN * FEAT + d0;
        const float4 E0 = *reinterpret_cast<const float4*>(ek + 0 * FEAT);
        const float4 E1 = *reinterpret_cast<const float4*>(ek + 1 * FEAT);
        const float4 E2 = *reinterpret_cast<const float4*>(ek + 2 * FEAT);
        const float4 E3 = *reinterpret_cast<const float4*>(ek + 3 * FEAT);
        const float4 E4 = *reinterpret_cast<const float4*>(ek + 4 * FEAT);
        const float4 EB = *reinterpret_cast<const float4*>(edge_bias + (size_t)n * FEAT + d0);

        const float4 G0 = *reinterpret_cast<const float4*>(&fk2[p][0 * FEAT + d0]);
        const float4 G1 = *reinterpret_cast<const float4*>(&fk2[p][1 * FEAT + d0]);
        const float4 G2 = *reinterpret_cast<const float4*>(&fk2[p][2 * FEAT + d0]);
        const float4 G3 = *reinterpret_cast<const float4*>(&fk2[p][3 * FEAT + d0]);
        const float4 G4 = *reinterpret_cast<const float4*>(&fk2[p][4 * FEAT + d0]);
        const float4 GB = *reinterpret_cast<const float4*>(&fk2[p][5 * FEAT + d0]);

        float* baseG = out + ((size_t)n * N_NB) * FEAT + d0;
        float* baseE = baseG + (size_t)N_EL * N_NB * FEAT;

#pragma unroll
        for (int j = 0; j < 8; ++j) {
            const int k = kg * 8 + j;
            const float4 v  = *reinterpret_cast<const float4*>(&feats[p][k * 8]);     // dx,dy,dz,dist (broadcast)
            const float2 se = *reinterpret_cast<const float2*>(&feats[p][k * 8 + 4]); // same,env (broadcast)

            float4 gamma, edge;
            gamma.x = (GB.x + G0.x * v.x + G1.x * v.y + G2.x * v.z + G3.x * v.w + G4.x * se.x) * se.y;
            gamma.y = (GB.y + G0.y * v.x + G1.y * v.y + G2.y * v.z + G3.y * v.w + G4.y * se.x) * se.y;
            gamma.z = (GB.z + G0.z * v.x + G1.z * v.y + G2.z * v.z + G3.z * v.w + G4.z * se.x) * se.y;
            gamma.w = (GB.w + G0.w * v.x + G1.w * v.y + G2.w * v.z + G3.w * v.w + G4.w * se.x) * se.y;

            edge.x = EB.x + E0.x * v.x + E1.x * v.y + E2.x * v.z + E3.x * v.w + E4.x * se.x;
            edge.y = EB.y + E0.y * v.x + E1.y * v.y + E2.y * v.z + E3.y * v.w + E4.y * se.x;
            edge.z = EB.z + E0.z * v.x + E1.z * v.y + E2.z * v.z + E3.z * v.w + E4.z * se.x;
            edge.w = EB.w + E0.w * v.x + E1.w * v.y + E2.w * v.z + E3.w * v.w + E4.w * se.x;

            __builtin_nontemporal_store(*reinterpret_cast<v4f*>(&gamma),
                                        reinterpret_cast<v4f*>(baseG + (size_t)k * FEAT));
            __builtin_nontemporal_store(*reinterpret_cast<v4f*>(&edge),
                                        reinterpret_cast<v4f*>(baseE + (size_t)k * FEAT));
        }
    }
}

extern "C" void kernel_launch(void* const* d_in, const int* in_sizes, int n_in,
                              void* d_out, int out_size, void* d_ws, size_t ws_size,
                              hipStream_t stream) {
    const float* r             = (const float*)d_in[0];
    const float* r_nb          = (const float*)d_in[1];
    const float* filter_kernel = (const float*)d_in[2];
    const float* filter_bias   = (const float*)d_in[3];
    const float* W_gamma       = (const float*)d_in[4];
    const float* edge_kernel_w = (const float*)d_in[5];
    const float* edge_bias     = (const float*)d_in[6];
    const int*   s             = (const int*)d_in[7];
    const int*   s_nb          = (const int*)d_in[8];
    float* out = (float*)d_out;

    EdgeFeatures_kernel<<<N_EL / PART, FEAT, 0, stream>>>(
        r, r_nb, filter_kernel, filter_bias, W_gamma, edge_kernel_w, edge_bias,
        s, s_nb, out);
}